// Round 8
// baseline (812.465 us; speedup 1.0000x reference)
//
#include <hip/hip_runtime.h>
#include <stdint.h>

typedef unsigned short u16;
typedef unsigned int   u32;
typedef short s16x8 __attribute__((ext_vector_type(8)));
typedef u16   u16x8 __attribute__((ext_vector_type(8)));
typedef u32   u32x4 __attribute__((ext_vector_type(4)));
typedef float f32x4 __attribute__((ext_vector_type(4)));

__device__ __forceinline__ u16 f2bf(float f) {
    u32 u = __float_as_uint(f);
    u32 r = u + 0x7fffu + ((u >> 16) & 1u);   // RNE
    return (u16)(r >> 16);
}
__device__ __forceinline__ float bf2f(u16 h) {
    return __uint_as_float(((u32)h) << 16);
}

// pack 2 f32 -> 2 bf16 (RNE), low word = a
__device__ __forceinline__ u32 cvtpk(float a, float b) {
    u32 r;
    asm("v_cvt_pk_bf16_f32 %0, %1, %2" : "=v"(r) : "v"(a), "v"(b));
    return r;
}
// swap a.lanes[32:63] <-> b.lanes[0:31]
__device__ __forceinline__ void swap32(u32& a, u32& b) {
#if __has_builtin(__builtin_amdgcn_permlane32_swap)
    auto r = __builtin_amdgcn_permlane32_swap(a, b, false, false);
    a = r[0]; b = r[1];
#else
    asm volatile("v_permlane32_swap_b32 %0, %1" : "+v"(a), "+v"(b));
#endif
}
// swap a's odd 16-rows <-> b's even 16-rows
__device__ __forceinline__ void swap16(u32& a, u32& b) {
#if __has_builtin(__builtin_amdgcn_permlane16_swap)
    auto r = __builtin_amdgcn_permlane16_swap(a, b, false, false);
    a = r[0]; b = r[1];
#else
    asm volatile("v_permlane16_swap_b32 %0, %1" : "+v"(a), "+v"(b));
#endif
}

// async global->LDS, 16B per lane. LDS dest = wave-uniform base + lane*16.
#define GLD16(gp, lp) __builtin_amdgcn_global_load_lds(                          \
    (const __attribute__((address_space(1))) void*)(uintptr_t)(gp),             \
    (__attribute__((address_space(3))) void*)(u32)(uintptr_t)(lp), 16, 0, 0)

#define FENCE asm volatile("" ::: "memory")

template<int N> __device__ __forceinline__ void waitv() {
    if constexpr (N == 0)      asm volatile("s_waitcnt vmcnt(0)" ::: "memory");
    else if constexpr (N == 6) asm volatile("s_waitcnt vmcnt(6)" ::: "memory");
    else                       asm volatile("s_waitcnt vmcnt(4)" ::: "memory");
}

// ---------------------------------------------------------------------------
// fp32 -> bf16 weight cast, 8 elems/thread
// ---------------------------------------------------------------------------
__global__ __launch_bounds__(256)
void cast_w(const float* __restrict__ in, u16* __restrict__ out, int n)
{
    const int i = (blockIdx.x * 256 + threadIdx.x) * 8;
    if (i >= n) return;
    f32x4 a = *(const f32x4*)(in + i);
    f32x4 b = *(const f32x4*)(in + i + 4);
    u16x8 o;
    o[0] = f2bf(a[0]); o[1] = f2bf(a[1]); o[2] = f2bf(a[2]); o[3] = f2bf(a[3]);
    o[4] = f2bf(b[0]); o[5] = f2bf(b[1]); o[6] = f2bf(b[2]); o[7] = f2bf(b[3]);
    *(u16x8*)(out + i) = o;
}

// ---------------------------------------------------------------------------
// RMSNorm: one block per row (C=2048), fp32 in -> bf16 out
// ---------------------------------------------------------------------------
__global__ __launch_bounds__(256)
void rmsnorm_k(const float* __restrict__ x, const float* __restrict__ wln,
               u16* __restrict__ out, int C)
{
    const int row = blockIdx.x;
    const int tid = threadIdx.x;
    const float* xr = x + (size_t)row * C;
    f32x4 a = *(const f32x4*)(xr + tid * 8);
    f32x4 b = *(const f32x4*)(xr + tid * 8 + 4);
    float s = a[0]*a[0] + a[1]*a[1] + a[2]*a[2] + a[3]*a[3]
            + b[0]*b[0] + b[1]*b[1] + b[2]*b[2] + b[3]*b[3];
    #pragma unroll
    for (int off = 1; off < 64; off <<= 1) s += __shfl_xor(s, off);
    __shared__ float red[4];
    if ((tid & 63) == 0) red[tid >> 6] = s;
    __syncthreads();
    float tot = red[0] + red[1] + red[2] + red[3];
    float inv = rsqrtf(tot / (float)C + 1e-6f);
    f32x4 wa = *(const f32x4*)(wln + tid * 8);
    f32x4 wb = *(const f32x4*)(wln + tid * 8 + 4);
    u16x8 o;
    o[0] = f2bf(a[0]*inv*wa[0]); o[1] = f2bf(a[1]*inv*wa[1]);
    o[2] = f2bf(a[2]*inv*wa[2]); o[3] = f2bf(a[3]*inv*wa[3]);
    o[4] = f2bf(b[0]*inv*wb[0]); o[5] = f2bf(b[1]*inv*wb[1]);
    o[6] = f2bf(b[2]*inv*wb[2]); o[7] = f2bf(b[3]*inv*wb[3]);
    *(u16x8*)(out + (size_t)row * C + tid * 8) = o;
}

// ---------------------------------------------------------------------------
// 3-buffer free-run GEMM (R8): C[M,N] = A[M,K] @ W[N,K]^T.
// Tile 128x256, BK=64, 8 waves (2M x 4N), per-wave 64x64 output.
// TRIPLE-buffered LDS (3 x 48KB): stage(t+2) targets the buffer whose readers
// (tile t-1) retired at this tile's entry barrier -> ONE barrier + one counted
// vmcnt(6) per K-tile; inside the tile, 16 ds_read + 32 MFMA free-run so the
// LDS pipe and MFMA pipe overlap across/within waves (the R4-R7 8-phase
// structure serialized them: LDS 40% + MFMA 39% burst-alternation).
// RAW: in-order vmcnt -> wait(6) at entry guarantees stage(t) landed (tail
// peels to vmcnt(0)); barrier makes it true for ALL waves' loads.
// WAR: stage(t+2) issues after the barrier retiring tile t-1's reads.
// MODE 0: bf16  1: bf16*scale  2: fp32 resid+acc  3: bf16 silu(aux)*acc
// ---------------------------------------------------------------------------
template<int MODE>
__global__ __launch_bounds__(512, 1)
void gemm3(const u16* __restrict__ A, const u16* __restrict__ W,
           const float* __restrict__ resid, const u16* __restrict__ aux,
           void* __restrict__ Cout, int M, int N, int K, float scale)
{
    constexpr int BM = 128;
    __shared__ __align__(16) u16 lds[3][(BM + 256) * 64];   // 3 x 48KB

    const int tid  = threadIdx.x;
    const int lane = tid & 63;
    const int w    = tid >> 6;
    const int wm   = w >> 2;
    const int wn   = w & 3;

    const int gx  = N >> 8;
    const int nwg = gridDim.x;
    const int sid = ((int)blockIdx.x & 7) * (nwg >> 3) + ((int)blockIdx.x >> 3);
    const int brow = (sid / gx) * BM;
    const int bcol = (sid % gx) * 256;

    const int KT = K >> 6;

    f32x4 acc[4][4] = {};

    // stage one full K-tile (6 GLD16/wave): A 128x64 + B 256x64, pre-swizzled src
    auto stageTile = [&](int buf, int kt) {
        #pragma unroll
        for (int g = 0; g < 2; ++g) {       // B halves (2 loads each)
            #pragma unroll
            for (int j = 0; j < 2; ++j) {
                const int p   = j * 64 + (tid >> 3);
                const int row = ((p & ~31) << 1) | (g * 32) | (p & 31);
                const int ch  = (tid & 7) ^ (row & 7);
                const u16* src = W + (size_t)(bcol + row) * K + kt * 64 + ch * 8;
                const int p0  = j * 64 + (w << 3);
                const int r0  = ((p0 & ~31) << 1) | (g * 32) | (p0 & 31);
                GLD16(src, &lds[buf][BM * 64] + r0 * 64);
            }
        }
        #pragma unroll
        for (int g = 0; g < 2; ++g) {       // A halves (1 load each)
            const int p   = tid >> 3;
            const int row = ((p & ~31) << 1) | (g * 32) | (p & 31);
            const int ch  = (tid & 7) ^ (row & 7);
            const u16* src = A + (size_t)(brow + row) * K + kt * 64 + ch * 8;
            const int p0  = w << 3;
            const int r0  = ((p0 & ~31) << 1) | (g * 32) | (p0 & 31);
            GLD16(src, &lds[buf][0] + r0 * 64);
        }
    };

    // prologue: tiles 0,1 in flight
    stageTile(0, 0);
    stageTile(1, 1);

    for (int t = 0; t < KT; ++t) {
        const int cur = t % 3;
        if (t == KT - 1) waitv<0>(); else waitv<6>();   // my stage(t) landed
        FENCE; __builtin_amdgcn_s_barrier(); FENCE;      // everyone's stage(t) landed;
                                                         // tile t-1 reads retired
        if (t + 2 < KT) stageTile((t + 2) % 3, t + 2);

        const u16* Ab = &lds[cur][0];
        const u16* Bb = &lds[cur][BM * 64];
        s16x8 af[4][2], bf[4][2];
        #pragma unroll
        for (int i = 0; i < 4; ++i)
            #pragma unroll
            for (int ks = 0; ks < 2; ++ks) {
                const int row = wm * 64 + i * 16 + (lane & 15);
                const int ch  = (ks * 4 + (lane >> 4)) ^ (row & 7);
                af[i][ks] = *(const s16x8*)(Ab + row * 64 + ch * 8);
            }
        #pragma unroll
        for (int j = 0; j < 4; ++j)
            #pragma unroll
            for (int ks = 0; ks < 2; ++ks) {
                const int row = wn * 64 + j * 16 + (lane & 15);
                const int ch  = (ks * 4 + (lane >> 4)) ^ (row & 7);
                bf[j][ks] = *(const s16x8*)(Bb + row * 64 + ch * 8);
            }
        __builtin_amdgcn_s_setprio(1);
        #pragma unroll
        for (int i = 0; i < 4; ++i)
            #pragma unroll
            for (int j = 0; j < 4; ++j)
                #pragma unroll
                for (int ks = 0; ks < 2; ++ks)
                    acc[i][j] = __builtin_amdgcn_mfma_f32_16x16x32_bf16(
                        af[i][ks], bf[j][ks], acc[i][j], 0, 0, 0);
        __builtin_amdgcn_s_setprio(0);
    }

    // epilogue: D layout col=lane&15, row=(lane>>4)*4+r
    const int er = (lane >> 4) * 4;
    const int ec = lane & 15;
    #pragma unroll
    for (int i = 0; i < 4; ++i) {
        #pragma unroll
        for (int j = 0; j < 4; ++j) {
            #pragma unroll
            for (int r = 0; r < 4; ++r) {
                const int row = brow + wm * 64 + i * 16 + er + r;
                const int col = bcol + wn * 64 + j * 16 + ec;
                const size_t idx = (size_t)row * N + col;
                const float va = acc[i][j][r];
                if (MODE == 0)      ((u16*)Cout)[idx] = f2bf(va);
                else if (MODE == 1) ((u16*)Cout)[idx] = f2bf(va * scale);
                else if (MODE == 2) ((float*)Cout)[idx] = resid[idx] + va;
                else {
                    const float g  = bf2f(aux[idx]);
                    const float sg = g / (1.0f + exp2f(-g * 1.4426950408889634f));
                    ((u16*)Cout)[idx] = f2bf(sg * va);
                }
            }
        }
    }
}

// ---------------------------------------------------------------------------
// Flash attention fwd (R7 structure, unchanged). Q pre-scaled by
// (1/sqrt(128))*log2(e). 8 waves x 32 q-rows; KV tiles of 64 keys; K/V dbuf
// LDS (XOR-swizzled); T14 async-stage; T12 swapped-QK^T in-register softmax.
// q,k,o: [b][t][h*128+d] bf16.  v PRE-TRANSPOSED: [h*128+d][b*2048+t].
// ---------------------------------------------------------------------------
__global__ __launch_bounds__(512, 2)
void flash_attn(const u16* __restrict__ q, const u16* __restrict__ k,
                const u16* __restrict__ vT, u16* __restrict__ o)
{
    __shared__ __align__(16) u16 Kt[2][64 * 128];
    __shared__ __align__(16) u16 Vt[2][128 * 64];
    const int tid  = threadIdx.x;
    const int lane = tid & 63;
    const int w    = tid >> 6;
    const int qtile = blockIdx.x;
    const int bh    = blockIdx.y;
    const int b = bh >> 4, h = bh & 15;
    const size_t head  = ((size_t)b * 2048) * 2048 + (size_t)h * 128;
    const size_t vbase = ((size_t)h * 128) * 4096 + (size_t)b * 2048;

    s16x8 qf[2][4];
    #pragma unroll
    for (int qi = 0; qi < 2; ++qi) {
        const int tq = qtile * 256 + w * 32 + qi * 16 + (lane & 15);
        const u16* qp = q + head + (size_t)tq * 2048 + (lane >> 4) * 8;
        #pragma unroll
        for (int dk = 0; dk < 4; ++dk) qf[qi][dk] = *(const s16x8*)(qp + dk * 32);
    }

    f32x4 oa[2][8] = {};
    float m_r[2] = {-1e30f, -1e30f};
    float l_r[2] = {0.f, 0.f};

    const int krow = tid >> 3;
    const int kcol = (tid & 7) * 16;
    const int vd   = tid >> 2;
    const int vk   = (tid & 3) * 16;
    const u16* kg = k + head + (size_t)krow * 2048 + kcol;
    const u16* vg = vT + vbase + (size_t)vd * 4096 + vk;
    const u32 kw0 = (u32)((krow * 256 + kcol * 2)      ^ ((krow & 7) << 4));
    const u32 kw1 = (u32)((krow * 256 + kcol * 2 + 16) ^ ((krow & 7) << 4));
    const u32 vw0 = (u32)((vd * 128 + vk * 2)          ^ ((vd & 7) << 4));
    const u32 vw1 = (u32)((vd * 128 + vk * 2 + 16)     ^ ((vd & 7) << 4));

    s16x8 kr0 = *(const s16x8*)(kg);
    s16x8 kr1 = *(const s16x8*)(kg + 8);
    s16x8 vr0 = *(const s16x8*)(vg);
    s16x8 vr1 = *(const s16x8*)(vg + 8);

    for (int kb = 0; kb < 32; ++kb) {
        const int cur = kb & 1;
        char* KtB = (char*)&Kt[cur][0];
        char* VtB = (char*)&Vt[cur][0];
        *(s16x8*)(KtB + kw0) = kr0;
        *(s16x8*)(KtB + kw1) = kr1;
        *(s16x8*)(VtB + vw0) = vr0;
        *(s16x8*)(VtB + vw1) = vr1;
        if (kb + 1 < 32) {
            const int k0n = (kb + 1) * 64;
            kr0 = *(const s16x8*)(kg + (size_t)k0n * 2048);
            kr1 = *(const s16x8*)(kg + (size_t)k0n * 2048 + 8);
            vr0 = *(const s16x8*)(vg + k0n);
            vr1 = *(const s16x8*)(vg + k0n + 8);
        }
        asm volatile("s_waitcnt lgkmcnt(0)" ::: "memory");
        __builtin_amdgcn_s_barrier();
        FENCE;

        f32x4 st[2][4] = {};
        __builtin_amdgcn_s_setprio(1);
        #pragma unroll
        for (int kt = 0; kt < 4; ++kt) {
            const int row = kt * 16 + (lane & 15);
            s16x8 kf[4];
            #pragma unroll
            for (int dk = 0; dk < 4; ++dk) {
                const int dcol = dk * 32 + (lane >> 4) * 8;
                kf[dk] = *(const s16x8*)(KtB + ((row * 256 + dcol * 2) ^ ((row & 7) << 4)));
            }
            #pragma unroll
            for (int qi = 0; qi < 2; ++qi)
                #pragma unroll
                for (int dk = 0; dk < 4; ++dk)
                    st[qi][kt] = __builtin_amdgcn_mfma_f32_16x16x32_bf16(kf[dk], qf[qi][dk], st[qi][kt], 0, 0, 0);
        }
        __builtin_amdgcn_s_setprio(0);

        float mx[2];
        #pragma unroll
        for (int qi = 0; qi < 2; ++qi) {
            float m0 = fmaxf(fmaxf(st[qi][0][0], st[qi][0][1]), fmaxf(st[qi][0][2], st[qi][0][3]));
            float m1 = fmaxf(fmaxf(st[qi][1][0], st[qi][1][1]), fmaxf(st[qi][1][2], st[qi][1][3]));
            float m2 = fmaxf(fmaxf(st[qi][2][0], st[qi][2][1]), fmaxf(st[qi][2][2], st[qi][2][3]));
            float m3 = fmaxf(fmaxf(st[qi][3][0], st[qi][3][1]), fmaxf(st[qi][3][2], st[qi][3][3]));
            float m0123 = fmaxf(fmaxf(m0, m1), fmaxf(m2, m3));
            m0123 = fmaxf(m0123, __shfl_xor(m0123, 16));
            m0123 = fmaxf(m0123, __shfl_xor(m0123, 32));
            mx[qi] = m0123;
        }
        const bool grow = (mx[0] > m_r[0] + 8.f) || (mx[1] > m_r[1] + 8.f);
        if (__any(grow)) {
            #pragma unroll
            for (int qi = 0; qi < 2; ++qi) {
                const float mn = fmaxf(m_r[qi], mx[qi]);
                const float sc = exp2f(m_r[qi] - mn);
                m_r[qi] = mn;
                l_r[qi] *= sc;
                const float s0 = __shfl(sc, (lane >> 4) * 4 + 0);
                const float s1 = __shfl(sc, (lane >> 4) * 4 + 1);
                const float s2 = __shfl(sc, (lane >> 4) * 4 + 2);
                const float s3 = __shfl(sc, (lane >> 4) * 4 + 3);
                #pragma unroll
                for (int ni = 0; ni < 8; ++ni) {
                    oa[qi][ni][0] *= s0; oa[qi][ni][1] *= s1;
                    oa[qi][ni][2] *= s2; oa[qi][ni][3] *= s3;
                }
            }
        }

        s16x8 pa[2][2];
        #pragma unroll
        for (int qi = 0; qi < 2; ++qi) {
            float sum = 0.f;
            #pragma unroll
            for (int kt = 0; kt < 4; ++kt)
                #pragma unroll
                for (int r = 0; r < 4; ++r) {
                    const float p = exp2f(st[qi][kt][r] - m_r[qi]);
                    st[qi][kt][r] = p;
                    sum += p;
                }
            sum += __shfl_xor(sum, 16);
            sum += __shfl_xor(sum, 32);
            l_r[qi] += sum;

            u32 q01[4], q23[4];
            #pragma unroll
            for (int kt = 0; kt < 4; ++kt) {
                q01[kt] = cvtpk(st[qi][kt][0], st[qi][kt][1]);
                q23[kt] = cvtpk(st[qi][kt][2], st[qi][kt][3]);
            }
            #pragma unroll
            for (int ks = 0; ks < 2; ++ks) {
                u32 X = q01[2 * ks], Y = q01[2 * ks + 1];
                swap32(X, Y); swap16(X, Y);
                u32 U = q23[2 * ks], V = q23[2 * ks + 1];
                swap32(U, V); swap16(U, V);
                u32x4 t; t[0] = X; t[1] = U; t[2] = Y; t[3] = V;
                pa[qi][ks] = __builtin_bit_cast(s16x8, t);
            }
        }

        __builtin_amdgcn_s_setprio(1);
        #pragma unroll
        for (int ks = 0; ks < 2; ++ks) {
            const int keyb = ks * 32 + (lane >> 4) * 8;
            #pragma unroll
            for (int ni = 0; ni < 8; ++ni) {
                const int dd = ni * 16 + (lane & 15);
                s16x8 vf = *(const s16x8*)(VtB + ((dd * 128 + keyb * 2) ^ ((dd & 7) << 4)));
                #pragma unroll
                for (int qi = 0; qi < 2; ++qi)
                    oa[qi][ni] = __builtin_amdgcn_mfma_f32_16x16x32_bf16(pa[qi][ks], vf, oa[qi][ni], 0, 0, 0);
            }
        }
        __builtin_amdgcn_s_setprio(0);
    }
    #pragma unroll
    for (int qi = 0; qi < 2; ++qi) {
        #pragma unroll
        for (int r = 0; r < 4; ++r) {
            const float inv = 1.0f / __shfl(l_r[qi], (lane >> 4) * 4 + r);
            const int tout = qtile * 256 + w * 32 + qi * 16 + (lane >> 4) * 4 + r;
            u16* op = o + head + (size_t)tout * 2048 + (lane & 15);
            #pragma unroll
            for (int ni = 0; ni < 8; ++ni)
                op[ni * 16] = f2bf(oa[qi][ni][r] * inv);
        }
    }
}

// ---------------------------------------------------------------------------
extern "C" void kernel_launch(void* const* d_in, const int* in_sizes, int n_in,
                              void* d_out, int out_size, void* d_ws, size_t ws_size,
                              hipStream_t stream)
{
    (void)in_sizes; (void)n_in; (void)out_size; (void)ws_size;
    const float* x    = (const float*)d_in[0];
    const float* wln1 = (const float*)d_in[1];
    const float* wq   = (const float*)d_in[2];
    const float* wk   = (const float*)d_in[3];
    const float* wv   = (const float*)d_in[4];
    const float* wo   = (const float*)d_in[5];
    const float* wln2 = (const float*)d_in[6];
    const float* wg   = (const float*)d_in[7];
    const float* wu   = (const float*)d_in[8];
    const float* wd   = (const float*)d_in[9];
    float* out = (float*)d_out;

    const size_t MB = 1024ull * 1024ull;
    char* ws = (char*)d_ws;
    u16*   arena = (u16*)(ws + 0);          // 32 MB: bf16 weight arena (reused)
    float* hbuf  = (float*)(ws + 32 * MB);  // 32 MB: x + attn residual (fp32)
    u16*   xn    = (u16*)(ws + 64 * MB);    // 16 MB: rmsnorm output (bf16)
    u16*   qb    = (u16*)(ws + 80 * MB);    // 16 MB
    u16*   kbuf  = (u16*)(ws + 96 * MB);    // 16 MB
    u16*   vT    = (u16*)(ws + 112 * MB);   // 16 MB: V transposed [h*128+d][b*2048+t]
    u16*   abuf  = (u16*)(ws + 128 * MB);   // 16 MB (ends 144 MB)
    u16*   gbuf  = (u16*)(ws + 80 * MB);    // 64 MB, aliases q..attn (dead then)

    const int M = 4096, C = 2048, I = 8192;
    const float qscale = 0.1275164899f;     // (1/sqrt(128)) * log2(e)
    dim3 blk(256);
    dim3 blk8(512);

    rmsnorm_k<<<M, blk, 0, stream>>>(x, wln1, xn, C);

    cast_w<<<(C * C) / 2048, blk, 0, stream>>>(wq, arena, C * C);
    gemm3<1><<<dim3((C / 256) * (M / 128)), blk8, 0, stream>>>(xn, arena, nullptr, nullptr, qb, M, C, C, qscale);
    cast_w<<<(C * C) / 2048, blk, 0, stream>>>(wk, arena, C * C);
    gemm3<0><<<dim3((C / 256) * (M / 128)), blk8, 0, stream>>>(xn, arena, nullptr, nullptr, kbuf, M, C, C, 1.f);
    cast_w<<<(C * C) / 2048, blk, 0, stream>>>(wv, arena, C * C);
    // V^T = Wv @ Xn^T : operand-swapped GEMM -> coalesced transposed output
    gemm3<0><<<dim3((M / 256) * (C / 128)), blk8, 0, stream>>>(arena, xn, nullptr, nullptr, vT, C, M, C, 1.f);

    flash_attn<<<dim3(2048 / 256, 32), blk8, 0, stream>>>(qb, kbuf, vT, abuf);

    cast_w<<<(C * C) / 2048, blk, 0, stream>>>(wo, arena, C * C);
    gemm3<2><<<dim3((C / 256) * (M / 128)), blk8, 0, stream>>>(abuf, arena, x, nullptr, hbuf, M, C, C, 1.f);

    rmsnorm_k<<<M, blk, 0, stream>>>(hbuf, wln2, xn, C);

    cast_w<<<(I * C) / 2048, blk, 0, stream>>>(wg, arena, I * C);
    gemm3<0><<<dim3((I / 256) * (M / 128)), blk8, 0, stream>>>(xn, arena, nullptr, nullptr, gbuf, M, I, C, 1.f);
    cast_w<<<(I * C) / 2048, blk, 0, stream>>>(wu, arena, I * C);
    gemm3<3><<<dim3((I / 256) * (M / 128)), blk8, 0, stream>>>(xn, arena, nullptr, gbuf, gbuf, M, I, C, 1.f);
    cast_w<<<(C * I) / 2048, blk, 0, stream>>>(wd, arena, C * I);
    gemm3<2><<<dim3((C / 256) * (M / 128)), blk8, 0, stream>>>(gbuf, arena, hbuf, nullptr, out, M, C, I, 1.f);
}

// Round 9
// 719.331 us; speedup vs baseline: 1.1295x; 1.1295x over previous
//
#include <hip/hip_runtime.h>
#include <stdint.h>

typedef unsigned short u16;
typedef unsigned int   u32;
typedef short s16x8 __attribute__((ext_vector_type(8)));
typedef u16   u16x8 __attribute__((ext_vector_type(8)));
typedef u32   u32x4 __attribute__((ext_vector_type(4)));
typedef float f32x4 __attribute__((ext_vector_type(4)));

__device__ __forceinline__ u16 f2bf(float f) {
    u32 u = __float_as_uint(f);
    u32 r = u + 0x7fffu + ((u >> 16) & 1u);   // RNE
    return (u16)(r >> 16);
}
__device__ __forceinline__ float bf2f(u16 h) {
    return __uint_as_float(((u32)h) << 16);
}

// pack 2 f32 -> 2 bf16 (RNE), low word = a
__device__ __forceinline__ u32 cvtpk(float a, float b) {
    u32 r;
    asm("v_cvt_pk_bf16_f32 %0, %1, %2" : "=v"(r) : "v"(a), "v"(b));
    return r;
}
// swap a.lanes[32:63] <-> b.lanes[0:31]
__device__ __forceinline__ void swap32(u32& a, u32& b) {
#if __has_builtin(__builtin_amdgcn_permlane32_swap)
    auto r = __builtin_amdgcn_permlane32_swap(a, b, false, false);
    a = r[0]; b = r[1];
#else
    asm volatile("v_permlane32_swap_b32 %0, %1" : "+v"(a), "+v"(b));
#endif
}
// swap a's odd 16-rows <-> b's even 16-rows
__device__ __forceinline__ void swap16(u32& a, u32& b) {
#if __has_builtin(__builtin_amdgcn_permlane16_swap)
    auto r = __builtin_amdgcn_permlane16_swap(a, b, false, false);
    a = r[0]; b = r[1];
#else
    asm volatile("v_permlane16_swap_b32 %0, %1" : "+v"(a), "+v"(b));
#endif
}

// async global->LDS, 16B per lane. LDS dest = wave-uniform base + lane*16.
#define GLD16(gp, lp) __builtin_amdgcn_global_load_lds(                          \
    (const __attribute__((address_space(1))) void*)(uintptr_t)(gp),             \
    (__attribute__((address_space(3))) void*)(u32)(uintptr_t)(lp), 16, 0, 0)

#define FENCE asm volatile("" ::: "memory")

template<int N> __device__ __forceinline__ void waitv() {
    if constexpr (N == 0)      asm volatile("s_waitcnt vmcnt(0)" ::: "memory");
    else if constexpr (N == 3) asm volatile("s_waitcnt vmcnt(3)" ::: "memory");
    else                       asm volatile("s_waitcnt vmcnt(4)" ::: "memory");
}

// ---------------------------------------------------------------------------
// fp32 -> bf16 weight cast, 8 elems/thread
// ---------------------------------------------------------------------------
__global__ __launch_bounds__(256)
void cast_w(const float* __restrict__ in, u16* __restrict__ out, int n)
{
    const int i = (blockIdx.x * 256 + threadIdx.x) * 8;
    if (i >= n) return;
    f32x4 a = *(const f32x4*)(in + i);
    f32x4 b = *(const f32x4*)(in + i + 4);
    u16x8 o;
    o[0] = f2bf(a[0]); o[1] = f2bf(a[1]); o[2] = f2bf(a[2]); o[3] = f2bf(a[3]);
    o[4] = f2bf(b[0]); o[5] = f2bf(b[1]); o[6] = f2bf(b[2]); o[7] = f2bf(b[3]);
    *(u16x8*)(out + i) = o;
}

// ---------------------------------------------------------------------------
// RMSNorm: one block per row (C=2048), fp32 in -> bf16 out
// ---------------------------------------------------------------------------
__global__ __launch_bounds__(256)
void rmsnorm_k(const float* __restrict__ x, const float* __restrict__ wln,
               u16* __restrict__ out, int C)
{
    const int row = blockIdx.x;
    const int tid = threadIdx.x;
    const float* xr = x + (size_t)row * C;
    f32x4 a = *(const f32x4*)(xr + tid * 8);
    f32x4 b = *(const f32x4*)(xr + tid * 8 + 4);
    float s = a[0]*a[0] + a[1]*a[1] + a[2]*a[2] + a[3]*a[3]
            + b[0]*b[0] + b[1]*b[1] + b[2]*b[2] + b[3]*b[3];
    #pragma unroll
    for (int off = 1; off < 64; off <<= 1) s += __shfl_xor(s, off);
    __shared__ float red[4];
    if ((tid & 63) == 0) red[tid >> 6] = s;
    __syncthreads();
    float tot = red[0] + red[1] + red[2] + red[3];
    float inv = rsqrtf(tot / (float)C + 1e-6f);
    f32x4 wa = *(const f32x4*)(wln + tid * 8);
    f32x4 wb = *(const f32x4*)(wln + tid * 8 + 4);
    u16x8 o;
    o[0] = f2bf(a[0]*inv*wa[0]); o[1] = f2bf(a[1]*inv*wa[1]);
    o[2] = f2bf(a[2]*inv*wa[2]); o[3] = f2bf(a[3]*inv*wa[3]);
    o[4] = f2bf(b[0]*inv*wb[0]); o[5] = f2bf(b[1]*inv*wb[1]);
    o[6] = f2bf(b[2]*inv*wb[2]); o[7] = f2bf(b[3]*inv*wb[3]);
    *(u16x8*)(out + (size_t)row * C + tid * 8) = o;
}

// ---------------------------------------------------------------------------
// 8-phase GEMM (R5 schedule, measured 152us MLP / 903TF): C = A @ W^T.
// Tile BM x 256, BK=64, 8 waves; Gray-code quadrant walk, fragments read once.
// Stage slots + counted vmcnt(2+AL) hazard-verified in R3/R5.
// MODE 0: bf16  1: bf16*scale  2: fp32 resid+acc  3: bf16 silu(aux)*acc
// ---------------------------------------------------------------------------
template<int MODE, int MR>
__global__ __launch_bounds__(512, 1)
void gemm8(const u16* __restrict__ A, const u16* __restrict__ W,
           const float* __restrict__ resid, const u16* __restrict__ aux,
           void* __restrict__ Cout, int M, int N, int K, float scale)
{
    constexpr int BM  = MR * 32;
    constexpr int MR2 = MR / 2;
    constexpr int SRA = MR * 8;           // A stripe rows
    constexpr int AL  = BM / 128;         // global_load_lds per A-group
    constexpr int WS  = 2 + AL;           // steady-state vmcnt
    __shared__ __align__(16) u16 lds[2][(BM + 256) * 64];

    const int tid  = threadIdx.x;
    const int lane = tid & 63;
    const int w    = tid >> 6;
    const int wm   = w >> 2;
    const int wn   = w & 3;

    const int gx  = N >> 8;
    const int nwg = gridDim.x;
    const int sid = ((int)blockIdx.x & 7) * (nwg >> 3) + ((int)blockIdx.x >> 3);
    const int brow = (sid / gx) * BM;
    const int bcol = (sid % gx) * 256;

    const int KT = K >> 6;
    const int NI = KT >> 1;

    f32x4 acc[MR][4] = {};

    auto stageA = [&](int buf, int g, int kt) {
        #pragma unroll
        for (int j = 0; j < AL; ++j) {
            const int p   = j * 64 + (tid >> 3);
            const int row = ((p & ~(SRA - 1)) << 1) | (g * SRA) | (p & (SRA - 1));
            const int ch  = (tid & 7) ^ (row & 7);
            const u16* src = A + (size_t)(brow + row) * K + kt * 64 + ch * 8;
            const int p0  = j * 64 + (w << 3);
            const int r0  = ((p0 & ~(SRA - 1)) << 1) | (g * SRA) | (p0 & (SRA - 1));
            GLD16(src, &lds[buf][0] + r0 * 64);
        }
    };
    auto stageB = [&](int buf, int g, int kt) {
        #pragma unroll
        for (int j = 0; j < 2; ++j) {
            const int p   = j * 64 + (tid >> 3);
            const int row = ((p & ~31) << 1) | (g * 32) | (p & 31);
            const int ch  = (tid & 7) ^ (row & 7);
            const u16* src = W + (size_t)(bcol + row) * K + kt * 64 + ch * 8;
            const int p0  = j * 64 + (w << 3);
            const int r0  = ((p0 & ~31) << 1) | (g * 32) | (p0 & 31);
            GLD16(src, &lds[buf][BM * 64] + r0 * 64);
        }
    };

#define LDA(AF, MH, Ab)                                                          \
    _Pragma("unroll") for (int f = 0; f < MR2; ++f)                              \
    _Pragma("unroll") for (int ks = 0; ks < 2; ++ks) {                           \
        const int row = wm * (BM / 2) + (MH) * (BM / 4) + f * 16 + (lane & 15);  \
        const int ch  = (ks * 4 + (lane >> 4)) ^ (row & 7);                      \
        AF[f][ks] = *(const s16x8*)((Ab) + row * 64 + ch * 8);                   \
    }
#define LDB(BQ, NH, Bb)                                                          \
    _Pragma("unroll") for (int g = 0; g < 2; ++g)                                \
    _Pragma("unroll") for (int ks = 0; ks < 2; ++ks) {                           \
        const int row = wn * 64 + (NH) * 32 + g * 16 + (lane & 15);              \
        const int ch  = (ks * 4 + (lane >> 4)) ^ (row & 7);                      \
        BQ[g][ks] = *(const s16x8*)((Bb) + row * 64 + ch * 8);                   \
    }
#define MFQ(AF, BQ, MH, NH)                                                      \
    __builtin_amdgcn_s_setprio(1);                                               \
    _Pragma("unroll") for (int f = 0; f < MR2; ++f)                              \
    _Pragma("unroll") for (int g = 0; g < 2; ++g)                                \
    _Pragma("unroll") for (int ks = 0; ks < 2; ++ks)                             \
        acc[(MH) * MR2 + f][(NH) * 2 + g] =                                      \
            __builtin_amdgcn_mfma_f32_16x16x32_bf16(                             \
                AF[f][ks], BQ[g][ks], acc[(MH) * MR2 + f][(NH) * 2 + g], 0, 0, 0); \
    __builtin_amdgcn_s_setprio(0);
#define BAR1 FENCE; __builtin_amdgcn_s_barrier(); FENCE
#define ENDP asm volatile("s_waitcnt lgkmcnt(0)" ::: "memory");                  \
             FENCE; __builtin_amdgcn_s_barrier(); FENCE

// one K-tile = 4 phases; fragments loaded once, held in regs (Gray walk)
#define KTILE(BUF, S1, S2, S3, S4, W4)                                           \
    {                                                                            \
        const u16* Ab = &lds[BUF][0];                                            \
        const u16* Bb = &lds[BUF][BM * 64];                                      \
        s16x8 afq[MR2][2], bq0[2][2], bq1[2][2];                                 \
        LDA(afq, 0, Ab) LDB(bq0, 0, Bb)                                          \
        S1; BAR1; MFQ(afq, bq0, 0, 0) ENDP;                                      \
        LDB(bq1, 1, Bb)                                                          \
        S2; BAR1; MFQ(afq, bq1, 0, 1) ENDP;                                      \
        LDA(afq, 1, Ab)                                                          \
        S3; BAR1; MFQ(afq, bq1, 1, 1) ENDP;                                      \
        S4; W4; BAR1; MFQ(afq, bq0, 1, 0) ENDP;                                  \
    }

    // prologue: tile0 complete into buf0; tile1's B0,A1 into buf1
    stageB(0, 0, 0); stageA(0, 1, 0); stageA(0, 0, 0); stageB(0, 1, 0);
    stageB(1, 0, 1); stageA(1, 1, 1);
    waitv<WS>();
    FENCE; __builtin_amdgcn_s_barrier(); FENCE;

    for (int it = 0; it < NI; ++it) {
        const int t1  = 2 * it + 1;
        const int t0n = 2 * it + 2;
        const int t1n = 2 * it + 3;
        const bool s0 = t0n < KT, s1 = t1n < KT;
        const bool last = (it == NI - 1);

        KTILE(0,
              { stageB(1, 1, t1); },
              { stageA(1, 0, t1); },
              { if (s0) stageB(0, 0, t0n); },
              { if (s0) stageA(0, 1, t0n); },
              { if (last) waitv<0>(); else waitv<WS>(); })
        KTILE(1,
              { if (s0) stageA(0, 0, t0n); },
              { if (s0) stageB(0, 1, t0n); },
              { if (s1) stageB(1, 0, t1n); },
              { if (s1) stageA(1, 1, t1n); },
              { if (!last) waitv<WS>(); })
    }
#undef KTILE
#undef LDA
#undef LDB
#undef MFQ
#undef BAR1
#undef ENDP

    // epilogue: D layout col=lane&15, row=(lane>>4)*4+r
    const int er = (lane >> 4) * 4;
    const int ec = lane & 15;
    #pragma unroll
    for (int i = 0; i < MR; ++i) {
        #pragma unroll
        for (int j = 0; j < 4; ++j) {
            #pragma unroll
            for (int r = 0; r < 4; ++r) {
                const int row = brow + wm * (BM / 2) + i * 16 + er + r;
                const int col = bcol + wn * 64 + j * 16 + ec;
                const size_t idx = (size_t)row * N + col;
                const float va = acc[i][j][r];
                if (MODE == 0)      ((u16*)Cout)[idx] = f2bf(va);
                else if (MODE == 1) ((u16*)Cout)[idx] = f2bf(va * scale);
                else if (MODE == 2) ((float*)Cout)[idx] = resid[idx] + va;
                else {
                    const float g  = bf2f(aux[idx]);
                    const float sg = g / (1.0f + exp2f(-g * 1.4426950408889634f));
                    ((u16*)Cout)[idx] = f2bf(sg * va);
                }
            }
        }
    }
}

// ---------------------------------------------------------------------------
// Flash attention fwd (R9): per-wave code identical to R7 (T12 swapped-QK^T
// in-register softmax, T13 defer-max, T14 async-stage, XOR-swizzled K/V dbuf)
// but RE-GRIDDED for 2 blocks/CU co-residency: 4 waves x 32 q-rows = 128
// q-rows/block, grid 16x32 = 512 blocks on 256 CUs (64KB LDS, 2 blocks/CU).
// Cross-block overlap: one block's softmax VALU runs under the other's MFMA
// (m114 mechanism) -- the in-block barrier no longer serializes the CU.
// q,k,o: [b][t][h*128+d] bf16.  v PRE-TRANSPOSED: [h*128+d][b*2048+t].
// ---------------------------------------------------------------------------
__global__ __launch_bounds__(256, 2)
void flash_attn(const u16* __restrict__ q, const u16* __restrict__ k,
                const u16* __restrict__ vT, u16* __restrict__ o)
{
    __shared__ __align__(16) u16 Kt[2][64 * 128];
    __shared__ __align__(16) u16 Vt[2][128 * 64];
    const int tid  = threadIdx.x;
    const int lane = tid & 63;
    const int w    = tid >> 6;             // 0..3
    const int qtile = blockIdx.x;          // 16 tiles of 128 q-rows
    const int bh    = blockIdx.y;
    const int b = bh >> 4, h = bh & 15;
    const size_t head  = ((size_t)b * 2048) * 2048 + (size_t)h * 128;
    const size_t vbase = ((size_t)h * 128) * 4096 + (size_t)b * 2048;

    s16x8 qf[2][4];
    #pragma unroll
    for (int qi = 0; qi < 2; ++qi) {
        const int tq = qtile * 128 + w * 32 + qi * 16 + (lane & 15);
        const u16* qp = q + head + (size_t)tq * 2048 + (lane >> 4) * 8;
        #pragma unroll
        for (int dk = 0; dk < 4; ++dk) qf[qi][dk] = *(const s16x8*)(qp + dk * 32);
    }

    f32x4 oa[2][8] = {};
    float m_r[2] = {-1e30f, -1e30f};
    float l_r[2] = {0.f, 0.f};

    // staging (256 threads, 4 chunks each):
    // K: row = tid>>2 (0..63), cols (tid&3)*32 + c*8
    // V: d   = tid>>1 (0..127), keys (tid&1)*32 + c*8
    const int krow = tid >> 2;
    const int kc0  = (tid & 3) * 32;
    const int vd   = tid >> 1;
    const int vk0  = (tid & 1) * 32;
    const u16* kg = k + head + (size_t)krow * 2048 + kc0;
    const u16* vg = vT + vbase + (size_t)vd * 4096 + vk0;
    u32 kwo[4], vwo[4];
    #pragma unroll
    for (int c = 0; c < 4; ++c) {
        kwo[c] = (u32)((krow * 256 + (kc0 + c * 8) * 2) ^ ((krow & 7) << 4));
        vwo[c] = (u32)((vd * 128 + (vk0 + c * 8) * 2)   ^ ((vd & 7) << 4));
    }

    // prefetch tile 0
    s16x8 kr[4], vr[4];
    #pragma unroll
    for (int c = 0; c < 4; ++c) {
        kr[c] = *(const s16x8*)(kg + c * 8);
        vr[c] = *(const s16x8*)(vg + c * 8);
    }

    for (int kb = 0; kb < 32; ++kb) {
        const int cur = kb & 1;
        char* KtB = (char*)&Kt[cur][0];
        char* VtB = (char*)&Vt[cur][0];
        #pragma unroll
        for (int c = 0; c < 4; ++c) {
            *(s16x8*)(KtB + kwo[c]) = kr[c];
            *(s16x8*)(VtB + vwo[c]) = vr[c];
        }
        if (kb + 1 < 32) {
            const int k0n = (kb + 1) * 64;
            #pragma unroll
            for (int c = 0; c < 4; ++c) {
                kr[c] = *(const s16x8*)(kg + (size_t)k0n * 2048 + c * 8);
                vr[c] = *(const s16x8*)(vg + k0n + c * 8);
            }
        }
        asm volatile("s_waitcnt lgkmcnt(0)" ::: "memory");
        __builtin_amdgcn_s_barrier();
        FENCE;

        // swapped S^T = K @ Q^T: st[qi][kt][r] = S[key=16kt+4hi+r][q=lane&15]
        f32x4 st[2][4] = {};
        __builtin_amdgcn_s_setprio(1);
        #pragma unroll
        for (int kt = 0; kt < 4; ++kt) {
            const int row = kt * 16 + (lane & 15);
            s16x8 kf[4];
            #pragma unroll
            for (int dk = 0; dk < 4; ++dk) {
                const int dcol = dk * 32 + (lane >> 4) * 8;
                kf[dk] = *(const s16x8*)(KtB + ((row * 256 + dcol * 2) ^ ((row & 7) << 4)));
            }
            #pragma unroll
            for (int qi = 0; qi < 2; ++qi)
                #pragma unroll
                for (int dk = 0; dk < 4; ++dk)
                    st[qi][kt] = __builtin_amdgcn_mfma_f32_16x16x32_bf16(kf[dk], qf[qi][dk], st[qi][kt], 0, 0, 0);
        }
        __builtin_amdgcn_s_setprio(0);

        float mx[2];
        #pragma unroll
        for (int qi = 0; qi < 2; ++qi) {
            float m0 = fmaxf(fmaxf(st[qi][0][0], st[qi][0][1]), fmaxf(st[qi][0][2], st[qi][0][3]));
            float m1 = fmaxf(fmaxf(st[qi][1][0], st[qi][1][1]), fmaxf(st[qi][1][2], st[qi][1][3]));
            float m2 = fmaxf(fmaxf(st[qi][2][0], st[qi][2][1]), fmaxf(st[qi][2][2], st[qi][2][3]));
            float m3 = fmaxf(fmaxf(st[qi][3][0], st[qi][3][1]), fmaxf(st[qi][3][2], st[qi][3][3]));
            float m0123 = fmaxf(fmaxf(m0, m1), fmaxf(m2, m3));
            m0123 = fmaxf(m0123, __shfl_xor(m0123, 16));
            m0123 = fmaxf(m0123, __shfl_xor(m0123, 32));
            mx[qi] = m0123;
        }
        const bool grow = (mx[0] > m_r[0] + 8.f) || (mx[1] > m_r[1] + 8.f);
        if (__any(grow)) {
            #pragma unroll
            for (int qi = 0; qi < 2; ++qi) {
                const float mn = fmaxf(m_r[qi], mx[qi]);
                const float sc = exp2f(m_r[qi] - mn);
                m_r[qi] = mn;
                l_r[qi] *= sc;
                const float s0 = __shfl(sc, (lane >> 4) * 4 + 0);
                const float s1 = __shfl(sc, (lane >> 4) * 4 + 1);
                const float s2 = __shfl(sc, (lane >> 4) * 4 + 2);
                const float s3 = __shfl(sc, (lane >> 4) * 4 + 3);
                #pragma unroll
                for (int ni = 0; ni < 8; ++ni) {
                    oa[qi][ni][0] *= s0; oa[qi][ni][1] *= s1;
                    oa[qi][ni][2] *= s2; oa[qi][ni][3] *= s3;
                }
            }
        }

        s16x8 pa[2][2];
        #pragma unroll
        for (int qi = 0; qi < 2; ++qi) {
            float sum = 0.f;
            #pragma unroll
            for (int kt = 0; kt < 4; ++kt)
                #pragma unroll
                for (int r = 0; r < 4; ++r) {
                    const float p = exp2f(st[qi][kt][r] - m_r[qi]);
                    st[qi][kt][r] = p;
                    sum += p;
                }
            sum += __shfl_xor(sum, 16);
            sum += __shfl_xor(sum, 32);
            l_r[qi] += sum;

            u32 q01[4], q23[4];
            #pragma unroll
            for (int kt = 0; kt < 4; ++kt) {
                q01[kt] = cvtpk(st[qi][kt][0], st[qi][kt][1]);
                q23[kt] = cvtpk(st[qi][kt][2], st[qi][kt][3]);
            }
            #pragma unroll
            for (int ks = 0; ks < 2; ++ks) {
                u32 X = q01[2 * ks], Y = q01[2 * ks + 1];
                swap32(X, Y); swap16(X, Y);
                u32 U = q23[2 * ks], V = q23[2 * ks + 1];
                swap32(U, V); swap16(U, V);
                u32x4 t; t[0] = X; t[1] = U; t[2] = Y; t[3] = V;
                pa[qi][ks] = __builtin_bit_cast(s16x8, t);
            }
        }

        __builtin_amdgcn_s_setprio(1);
        #pragma unroll
        for (int ks = 0; ks < 2; ++ks) {
            const int keyb = ks * 32 + (lane >> 4) * 8;
            #pragma unroll
            for (int ni = 0; ni < 8; ++ni) {
                const int dd = ni * 16 + (lane & 15);
                s16x8 vf = *(const s16x8*)(VtB + ((dd * 128 + keyb * 2) ^ ((dd & 7) << 4)));
                #pragma unroll
                for (int qi = 0; qi < 2; ++qi)
                    oa[qi][ni] = __builtin_amdgcn_mfma_f32_16x16x32_bf16(pa[qi][ks], vf, oa[qi][ni], 0, 0, 0);
            }
        }
        __builtin_amdgcn_s_setprio(0);
    }
    #pragma unroll
    for (int qi = 0; qi < 2; ++qi) {
        #pragma unroll
        for (int r = 0; r < 4; ++r) {
            const float inv = 1.0f / __shfl(l_r[qi], (lane >> 4) * 4 + r);
            const int tout = qtile * 128 + w * 32 + qi * 16 + (lane >> 4) * 4 + r;
            u16* op = o + head + (size_t)tout * 2048 + (lane & 15);
            #pragma unroll
            for (int ni = 0; ni < 8; ++ni)
                op[ni * 16] = f2bf(oa[qi][ni][r] * inv);
        }
    }
}

// ---------------------------------------------------------------------------
extern "C" void kernel_launch(void* const* d_in, const int* in_sizes, int n_in,
                              void* d_out, int out_size, void* d_ws, size_t ws_size,
                              hipStream_t stream)
{
    (void)in_sizes; (void)n_in; (void)out_size; (void)ws_size;
    const float* x    = (const float*)d_in[0];
    const float* wln1 = (const float*)d_in[1];
    const float* wq   = (const float*)d_in[2];
    const float* wk   = (const float*)d_in[3];
    const float* wv   = (const float*)d_in[4];
    const float* wo   = (const float*)d_in[5];
    const float* wln2 = (const float*)d_in[6];
    const float* wg   = (const float*)d_in[7];
    const float* wu   = (const float*)d_in[8];
    const float* wd   = (const float*)d_in[9];
    float* out = (float*)d_out;

    const size_t MB = 1024ull * 1024ull;
    char* ws = (char*)d_ws;
    u16*   arena = (u16*)(ws + 0);          // 32 MB: bf16 weight arena (reused)
    float* hbuf  = (float*)(ws + 32 * MB);  // 32 MB: x + attn residual (fp32)
    u16*   xn    = (u16*)(ws + 64 * MB);    // 16 MB: rmsnorm output (bf16)
    u16*   qb    = (u16*)(ws + 80 * MB);    // 16 MB
    u16*   kbuf  = (u16*)(ws + 96 * MB);    // 16 MB
    u16*   vT    = (u16*)(ws + 112 * MB);   // 16 MB: V transposed [h*128+d][b*2048+t]
    u16*   abuf  = (u16*)(ws + 128 * MB);   // 16 MB (ends 144 MB)
    u16*   gbuf  = (u16*)(ws + 80 * MB);    // 64 MB, aliases q..attn (dead then)

    const int M = 4096, C = 2048, I = 8192;
    const float qscale = 0.1275164899f;     // (1/sqrt(128)) * log2(e)
    dim3 blk(256);
    dim3 blk8(512);

    rmsnorm_k<<<M, blk, 0, stream>>>(x, wln1, xn, C);

    cast_w<<<(C * C) / 2048, blk, 0, stream>>>(wq, arena, C * C);
    gemm8<1, 4><<<dim3((C / 256) * (M / 128)), blk8, 0, stream>>>(xn, arena, nullptr, nullptr, qb, M, C, C, qscale);
    cast_w<<<(C * C) / 2048, blk, 0, stream>>>(wk, arena, C * C);
    gemm8<0, 4><<<dim3((C / 256) * (M / 128)), blk8, 0, stream>>>(xn, arena, nullptr, nullptr, kbuf, M, C, C, 1.f);
    cast_w<<<(C * C) / 2048, blk, 0, stream>>>(wv, arena, C * C);
    // V^T = Wv @ Xn^T : operand-swapped GEMM -> coalesced transposed output
    gemm8<0, 4><<<dim3((M / 256) * (C / 128)), blk8, 0, stream>>>(arena, xn, nullptr, nullptr, vT, C, M, C, 1.f);

    flash_attn<<<dim3(2048 / 128, 32), blk, 0, stream>>>(qb, kbuf, vT, abuf);

    cast_w<<<(C * C) / 2048, blk, 0, stream>>>(wo, arena, C * C);
    gemm8<2, 4><<<dim3((C / 256) * (M / 128)), blk8, 0, stream>>>(abuf, arena, x, nullptr, hbuf, M, C, C, 1.f);

    rmsnorm_k<<<M, blk, 0, stream>>>(hbuf, wln2, xn, C);

    cast_w<<<(I * C) / 2048, blk, 0, stream>>>(wg, arena, I * C);
    gemm8<0, 8><<<dim3((I / 256) * (M / 256)), blk8, 0, stream>>>(xn, arena, nullptr, nullptr, gbuf, M, I, C, 1.f);
    cast_w<<<(I * C) / 2048, blk, 0, stream>>>(wu, arena, I * C);
    gemm8<3, 8><<<dim3((I / 256) * (M / 256)), blk8, 0, stream>>>(xn, arena, nullptr, gbuf, gbuf, M, I, C, 1.f);
    cast_w<<<(C * I) / 2048, blk, 0, stream>>>(wd, arena, C * I);
    gemm8<2, 4><<<dim3((C / 256) * (M / 128)), blk8, 0, stream>>>(gbuf, arena, hbuf, nullptr, out, M, C, I, 1.f);
}

// Round 10
// 717.889 us; speedup vs baseline: 1.1317x; 1.0020x over previous
//
#include <hip/hip_runtime.h>
#include <stdint.h>

typedef unsigned short u16;
typedef unsigned int   u32;
typedef short s16x8 __attribute__((ext_vector_type(8)));
typedef u16   u16x8 __attribute__((ext_vector_type(8)));
typedef u32   u32x4 __attribute__((ext_vector_type(4)));
typedef float f32x4 __attribute__((ext_vector_type(4)));

__device__ __forceinline__ u16 f2bf(float f) {
    u32 u = __float_as_uint(f);
    u32 r = u + 0x7fffu + ((u >> 16) & 1u);   // RNE
    return (u16)(r >> 16);
}
__device__ __forceinline__ float bf2f(u16 h) {
    return __uint_as_float(((u32)h) << 16);
}

// pack 2 f32 -> 2 bf16 (RNE), low word = a
__device__ __forceinline__ u32 cvtpk(float a, float b) {
    u32 r;
    asm("v_cvt_pk_bf16_f32 %0, %1, %2" : "=v"(r) : "v"(a), "v"(b));
    return r;
}
// swap a.lanes[32:63] <-> b.lanes[0:31]
__device__ __forceinline__ void swap32(u32& a, u32& b) {
#if __has_builtin(__builtin_amdgcn_permlane32_swap)
    auto r = __builtin_amdgcn_permlane32_swap(a, b, false, false);
    a = r[0]; b = r[1];
#else
    asm volatile("v_permlane32_swap_b32 %0, %1" : "+v"(a), "+v"(b));
#endif
}
// swap a's odd 16-rows <-> b's even 16-rows
__device__ __forceinline__ void swap16(u32& a, u32& b) {
#if __has_builtin(__builtin_amdgcn_permlane16_swap)
    auto r = __builtin_amdgcn_permlane16_swap(a, b, false, false);
    a = r[0]; b = r[1];
#else
    asm volatile("v_permlane16_swap_b32 %0, %1" : "+v"(a), "+v"(b));
#endif
}

// async global->LDS, 16B per lane. LDS dest = wave-uniform base + lane*16.
#define GLD16(gp, lp) __builtin_amdgcn_global_load_lds(                          \
    (const __attribute__((address_space(1))) void*)(uintptr_t)(gp),             \
    (__attribute__((address_space(3))) void*)(u32)(uintptr_t)(lp), 16, 0, 0)

#define FENCE asm volatile("" ::: "memory")

template<int N> __device__ __forceinline__ void waitv() {
    if constexpr (N == 0)      asm volatile("s_waitcnt vmcnt(0)" ::: "memory");
    else if constexpr (N == 2) asm volatile("s_waitcnt vmcnt(2)" ::: "memory");
    else if constexpr (N == 3) asm volatile("s_waitcnt vmcnt(3)" ::: "memory");
    else                       asm volatile("s_waitcnt vmcnt(4)" ::: "memory");
}

// ---------------------------------------------------------------------------
// fp32 -> bf16 weight cast, 8 elems/thread
// ---------------------------------------------------------------------------
__global__ __launch_bounds__(256)
void cast_w(const float* __restrict__ in, u16* __restrict__ out, int n)
{
    const int i = (blockIdx.x * 256 + threadIdx.x) * 8;
    if (i >= n) return;
    f32x4 a = *(const f32x4*)(in + i);
    f32x4 b = *(const f32x4*)(in + i + 4);
    u16x8 o;
    o[0] = f2bf(a[0]); o[1] = f2bf(a[1]); o[2] = f2bf(a[2]); o[3] = f2bf(a[3]);
    o[4] = f2bf(b[0]); o[5] = f2bf(b[1]); o[6] = f2bf(b[2]); o[7] = f2bf(b[3]);
    *(u16x8*)(out + i) = o;
}

// ---------------------------------------------------------------------------
// RMSNorm: one block per row (C=2048), fp32 in -> bf16 out
// ---------------------------------------------------------------------------
__global__ __launch_bounds__(256)
void rmsnorm_k(const float* __restrict__ x, const float* __restrict__ wln,
               u16* __restrict__ out, int C)
{
    const int row = blockIdx.x;
    const int tid = threadIdx.x;
    const float* xr = x + (size_t)row * C;
    f32x4 a = *(const f32x4*)(xr + tid * 8);
    f32x4 b = *(const f32x4*)(xr + tid * 8 + 4);
    float s = a[0]*a[0] + a[1]*a[1] + a[2]*a[2] + a[3]*a[3]
            + b[0]*b[0] + b[1]*b[1] + b[2]*b[2] + b[3]*b[3];
    #pragma unroll
    for (int off = 1; off < 64; off <<= 1) s += __shfl_xor(s, off);
    __shared__ float red[4];
    if ((tid & 63) == 0) red[tid >> 6] = s;
    __syncthreads();
    float tot = red[0] + red[1] + red[2] + red[3];
    float inv = rsqrtf(tot / (float)C + 1e-6f);
    f32x4 wa = *(const f32x4*)(wln + tid * 8);
    f32x4 wb = *(const f32x4*)(wln + tid * 8 + 4);
    u16x8 o;
    o[0] = f2bf(a[0]*inv*wa[0]); o[1] = f2bf(a[1]*inv*wa[1]);
    o[2] = f2bf(a[2]*inv*wa[2]); o[3] = f2bf(a[3]*inv*wa[3]);
    o[4] = f2bf(b[0]*inv*wb[0]); o[5] = f2bf(b[1]*inv*wb[1]);
    o[6] = f2bf(b[2]*inv*wb[2]); o[7] = f2bf(b[3]*inv*wb[3]);
    *(u16x8*)(out + (size_t)row * C + tid * 8) = o;
}

// ---------------------------------------------------------------------------
// Pipelined 8-phase GEMM (R10): C[M,N] = A[M,K] @ W[N,K]^T.
// Tile BM x 256, BK=64, 8 waves, Gray-code quadrant walk. Each phase:
//   {barrier; lgkm(0); MFMA (frags read LAST phase); ds_read next frags;
//    stage slot; [vmcnt(2) at P4/P8]}
// -> ds_reads issue while the matrix pipe executes (independent pipes),
// un-serializing LDS and MFMA (R4-R9 structures alternated bursts).
// af reloaded IN PLACE after last use (no extra VGPR); bq double-buffered.
// Hazards (verified): every stage >=1 barrier after its region's reader
// drain (entry lgkm); every pre-read covered by vmcnt(2) at P4/P8 PLUS >=1
// barrier (cross-wave transfer). Prologue 7 slots + vmcnt(0); tail peels
// P4 to vmcnt(0), skips P8 pre-read.
// MODE 0: bf16  1: bf16*scale  2: fp32 resid+acc  3: bf16 silu(aux)*acc
// ---------------------------------------------------------------------------
template<int MODE, int MR>
__global__ __launch_bounds__(512, 1)
void gemm8(const u16* __restrict__ A, const u16* __restrict__ W,
           const float* __restrict__ resid, const u16* __restrict__ aux,
           void* __restrict__ Cout, int M, int N, int K, float scale)
{
    constexpr int BM  = MR * 32;
    constexpr int MR2 = MR / 2;
    constexpr int SRA = MR * 8;           // A stripe rows
    constexpr int AL  = BM / 128;         // global_load_lds per A-group
    __shared__ __align__(16) u16 lds[2][(BM + 256) * 64];

    const int tid  = threadIdx.x;
    const int lane = tid & 63;
    const int w    = tid >> 6;
    const int wm   = w >> 2;
    const int wn   = w & 3;

    const int gx  = N >> 8;
    const int nwg = gridDim.x;
    const int sid = ((int)blockIdx.x & 7) * (nwg >> 3) + ((int)blockIdx.x >> 3);
    const int brow = (sid / gx) * BM;
    const int bcol = (sid % gx) * 256;

    const int KT = K >> 6;
    const int NI = KT >> 1;

    f32x4 acc[MR][4] = {};

    auto stageA = [&](int buf, int g, int kt) {
        #pragma unroll
        for (int j = 0; j < AL; ++j) {
            const int p   = j * 64 + (tid >> 3);
            const int row = ((p & ~(SRA - 1)) << 1) | (g * SRA) | (p & (SRA - 1));
            const int ch  = (tid & 7) ^ (row & 7);
            const u16* src = A + (size_t)(brow + row) * K + kt * 64 + ch * 8;
            const int p0  = j * 64 + (w << 3);
            const int r0  = ((p0 & ~(SRA - 1)) << 1) | (g * SRA) | (p0 & (SRA - 1));
            GLD16(src, &lds[buf][0] + r0 * 64);
        }
    };
    auto stageB = [&](int buf, int g, int kt) {
        #pragma unroll
        for (int j = 0; j < 2; ++j) {
            const int p   = j * 64 + (tid >> 3);
            const int row = ((p & ~31) << 1) | (g * 32) | (p & 31);
            const int ch  = (tid & 7) ^ (row & 7);
            const u16* src = W + (size_t)(bcol + row) * K + kt * 64 + ch * 8;
            const int p0  = j * 64 + (w << 3);
            const int r0  = ((p0 & ~31) << 1) | (g * 32) | (p0 & 31);
            GLD16(src, &lds[buf][BM * 64] + r0 * 64);
        }
    };

#define LDAF(AF, MH, BUF)                                                        \
    _Pragma("unroll") for (int f = 0; f < MR2; ++f)                              \
    _Pragma("unroll") for (int ks = 0; ks < 2; ++ks) {                           \
        const int row = wm * (BM / 2) + (MH) * (BM / 4) + f * 16 + (lane & 15);  \
        const int ch  = (ks * 4 + (lane >> 4)) ^ (row & 7);                      \
        AF[f][ks] = *(const s16x8*)(&lds[BUF][0] + row * 64 + ch * 8);           \
    }
#define LDBF(BQ, NH, BUF)                                                        \
    _Pragma("unroll") for (int g = 0; g < 2; ++g)                                \
    _Pragma("unroll") for (int ks = 0; ks < 2; ++ks) {                           \
        const int row = wn * 64 + (NH) * 32 + g * 16 + (lane & 15);              \
        const int ch  = (ks * 4 + (lane >> 4)) ^ (row & 7);                      \
        BQ[g][ks] = *(const s16x8*)(&lds[BUF][BM * 64] + row * 64 + ch * 8);     \
    }
#define MFQ(AF, BQ, MH, NH)                                                      \
    __builtin_amdgcn_s_setprio(1);                                               \
    _Pragma("unroll") for (int f = 0; f < MR2; ++f)                              \
    _Pragma("unroll") for (int g = 0; g < 2; ++g)                                \
    _Pragma("unroll") for (int ks = 0; ks < 2; ++ks)                             \
        acc[(MH) * MR2 + f][(NH) * 2 + g] =                                      \
            __builtin_amdgcn_mfma_f32_16x16x32_bf16(                             \
                AF[f][ks], BQ[g][ks], acc[(MH) * MR2 + f][(NH) * 2 + g], 0, 0, 0); \
    __builtin_amdgcn_s_setprio(0);
#define PH_ENTRY FENCE; __builtin_amdgcn_s_barrier();                            \
    asm volatile("s_waitcnt lgkmcnt(0)" ::: "memory"); FENCE

    s16x8 af[MR2][2], bqA[2][2], bqB[2][2];

    // prologue: t0 full -> buf0; t1's B0,A0,B1 -> buf1 (A1 staged at P1).
    stageB(0, 0, 0); stageA(0, 0, 0); stageB(0, 1, 0); stageA(0, 1, 0);
    stageB(1, 0, 1); stageA(1, 0, 1); stageB(1, 1, 1);
    waitv<0>();
    FENCE; __builtin_amdgcn_s_barrier(); FENCE;
    LDAF(af, 0, 0) LDBF(bqA, 0, 0)

    for (int it = 0; it < NI; ++it) {
        const int t1  = 2 * it + 1;
        const int t0n = 2 * it + 2;
        const int t1n = 2 * it + 3;
        const bool last = (it == NI - 1);

        // P1: Q(0,0) buf0
        PH_ENTRY; MFQ(af, bqA, 0, 0)
        LDBF(bqB, 1, 0)
        stageA(1, 1, t1);                       // buf1-A1 (t1), read @P6 body
        // P2: Q(0,1) buf0
        PH_ENTRY; MFQ(af, bqB, 0, 1)
        LDAF(af, 1, 0)
        if (!last) stageB(0, 0, t0n);
        // P3: Q(1,1) buf0
        PH_ENTRY; MFQ(af, bqB, 1, 1)
        if (!last) stageA(0, 0, t0n);
        // P4: Q(1,0) buf0 -> buffer switch pre-read
        PH_ENTRY; MFQ(af, bqA, 1, 0)
        if (!last) stageB(0, 1, t0n);
        if (last) { waitv<0>(); } else { waitv<2>(); }
        LDAF(af, 0, 1) LDBF(bqA, 0, 1)
        // P5: Q(0,0) buf1
        PH_ENTRY; MFQ(af, bqA, 0, 0)
        LDBF(bqB, 1, 1)
        if (!last) stageA(0, 1, t0n);
        // P6: Q(0,1) buf1
        PH_ENTRY; MFQ(af, bqB, 0, 1)
        LDAF(af, 1, 1)
        if (!last) stageB(1, 0, t1n);
        // P7: Q(1,1) buf1
        PH_ENTRY; MFQ(af, bqB, 1, 1)
        if (!last) stageA(1, 0, t1n);
        // P8: Q(1,0) buf1 -> buffer switch pre-read (skip on last)
        PH_ENTRY; MFQ(af, bqA, 1, 0)
        if (!last) {
            stageB(1, 1, t1n);
            waitv<2>();
            LDAF(af, 0, 0) LDBF(bqA, 0, 0)
        }
    }
#undef LDAF
#undef LDBF
#undef MFQ
#undef PH_ENTRY

    // epilogue: D layout col=lane&15, row=(lane>>4)*4+r
    const int er = (lane >> 4) * 4;
    const int ec = lane & 15;
    #pragma unroll
    for (int i = 0; i < MR; ++i) {
        #pragma unroll
        for (int j = 0; j < 4; ++j) {
            #pragma unroll
            for (int r = 0; r < 4; ++r) {
                const int row = brow + wm * (BM / 2) + i * 16 + er + r;
                const int col = bcol + wn * 64 + j * 16 + ec;
                const size_t idx = (size_t)row * N + col;
                const float va = acc[i][j][r];
                if (MODE == 0)      ((u16*)Cout)[idx] = f2bf(va);
                else if (MODE == 1) ((u16*)Cout)[idx] = f2bf(va * scale);
                else if (MODE == 2) ((float*)Cout)[idx] = resid[idx] + va;
                else {
                    const float g  = bf2f(aux[idx]);
                    const float sg = g / (1.0f + exp2f(-g * 1.4426950408889634f));
                    ((u16*)Cout)[idx] = f2bf(sg * va);
                }
            }
        }
    }
}

// ---------------------------------------------------------------------------
// Flash attention fwd (R9 structure, unchanged): 4 waves x 32 q-rows = 128
// q-rows/block, 512 blocks = 2 blocks/CU; T12 swapped-QK^T in-register
// softmax, T13 defer-max, T14 async-stage, XOR-swizzled K/V dbuf.
// q,k,o: [b][t][h*128+d] bf16.  v PRE-TRANSPOSED: [h*128+d][b*2048+t].
// ---------------------------------------------------------------------------
__global__ __launch_bounds__(256, 2)
void flash_attn(const u16* __restrict__ q, const u16* __restrict__ k,
                const u16* __restrict__ vT, u16* __restrict__ o)
{
    __shared__ __align__(16) u16 Kt[2][64 * 128];
    __shared__ __align__(16) u16 Vt[2][128 * 64];
    const int tid  = threadIdx.x;
    const int lane = tid & 63;
    const int w    = tid >> 6;
    const int qtile = blockIdx.x;
    const int bh    = blockIdx.y;
    const int b = bh >> 4, h = bh & 15;
    const size_t head  = ((size_t)b * 2048) * 2048 + (size_t)h * 128;
    const size_t vbase = ((size_t)h * 128) * 4096 + (size_t)b * 2048;

    s16x8 qf[2][4];
    #pragma unroll
    for (int qi = 0; qi < 2; ++qi) {
        const int tq = qtile * 128 + w * 32 + qi * 16 + (lane & 15);
        const u16* qp = q + head + (size_t)tq * 2048 + (lane >> 4) * 8;
        #pragma unroll
        for (int dk = 0; dk < 4; ++dk) qf[qi][dk] = *(const s16x8*)(qp + dk * 32);
    }

    f32x4 oa[2][8] = {};
    float m_r[2] = {-1e30f, -1e30f};
    float l_r[2] = {0.f, 0.f};

    const int krow = tid >> 2;
    const int kc0  = (tid & 3) * 32;
    const int vd   = tid >> 1;
    const int vk0  = (tid & 1) * 32;
    const u16* kg = k + head + (size_t)krow * 2048 + kc0;
    const u16* vg = vT + vbase + (size_t)vd * 4096 + vk0;
    u32 kwo[4], vwo[4];
    #pragma unroll
    for (int c = 0; c < 4; ++c) {
        kwo[c] = (u32)((krow * 256 + (kc0 + c * 8) * 2) ^ ((krow & 7) << 4));
        vwo[c] = (u32)((vd * 128 + (vk0 + c * 8) * 2)   ^ ((vd & 7) << 4));
    }

    s16x8 kr[4], vr[4];
    #pragma unroll
    for (int c = 0; c < 4; ++c) {
        kr[c] = *(const s16x8*)(kg + c * 8);
        vr[c] = *(const s16x8*)(vg + c * 8);
    }

    for (int kb = 0; kb < 32; ++kb) {
        const int cur = kb & 1;
        char* KtB = (char*)&Kt[cur][0];
        char* VtB = (char*)&Vt[cur][0];
        #pragma unroll
        for (int c = 0; c < 4; ++c) {
            *(s16x8*)(KtB + kwo[c]) = kr[c];
            *(s16x8*)(VtB + vwo[c]) = vr[c];
        }
        if (kb + 1 < 32) {
            const int k0n = (kb + 1) * 64;
            #pragma unroll
            for (int c = 0; c < 4; ++c) {
                kr[c] = *(const s16x8*)(kg + (size_t)k0n * 2048 + c * 8);
                vr[c] = *(const s16x8*)(vg + k0n + c * 8);
            }
        }
        asm volatile("s_waitcnt lgkmcnt(0)" ::: "memory");
        __builtin_amdgcn_s_barrier();
        FENCE;

        f32x4 st[2][4] = {};
        __builtin_amdgcn_s_setprio(1);
        #pragma unroll
        for (int kt = 0; kt < 4; ++kt) {
            const int row = kt * 16 + (lane & 15);
            s16x8 kf[4];
            #pragma unroll
            for (int dk = 0; dk < 4; ++dk) {
                const int dcol = dk * 32 + (lane >> 4) * 8;
                kf[dk] = *(const s16x8*)(KtB + ((row * 256 + dcol * 2) ^ ((row & 7) << 4)));
            }
            #pragma unroll
            for (int qi = 0; qi < 2; ++qi)
                #pragma unroll
                for (int dk = 0; dk < 4; ++dk)
                    st[qi][kt] = __builtin_amdgcn_mfma_f32_16x16x32_bf16(kf[dk], qf[qi][dk], st[qi][kt], 0, 0, 0);
        }
        __builtin_amdgcn_s_setprio(0);

        float mx[2];
        #pragma unroll
        for (int qi = 0; qi < 2; ++qi) {
            float m0 = fmaxf(fmaxf(st[qi][0][0], st[qi][0][1]), fmaxf(st[qi][0][2], st[qi][0][3]));
            float m1 = fmaxf(fmaxf(st[qi][1][0], st[qi][1][1]), fmaxf(st[qi][1][2], st[qi][1][3]));
            float m2 = fmaxf(fmaxf(st[qi][2][0], st[qi][2][1]), fmaxf(st[qi][2][2], st[qi][2][3]));
            float m3 = fmaxf(fmaxf(st[qi][3][0], st[qi][3][1]), fmaxf(st[qi][3][2], st[qi][3][3]));
            float m0123 = fmaxf(fmaxf(m0, m1), fmaxf(m2, m3));
            m0123 = fmaxf(m0123, __shfl_xor(m0123, 16));
            m0123 = fmaxf(m0123, __shfl_xor(m0123, 32));
            mx[qi] = m0123;
        }
        const bool grow = (mx[0] > m_r[0] + 8.f) || (mx[1] > m_r[1] + 8.f);
        if (__any(grow)) {
            #pragma unroll
            for (int qi = 0; qi < 2; ++qi) {
                const float mn = fmaxf(m_r[qi], mx[qi]);
                const float sc = exp2f(m_r[qi] - mn);
                m_r[qi] = mn;
                l_r[qi] *= sc;
                const float s0 = __shfl(sc, (lane >> 4) * 4 + 0);
                const float s1 = __shfl(sc, (lane >> 4) * 4 + 1);
                const float s2 = __shfl(sc, (lane >> 4) * 4 + 2);
                const float s3 = __shfl(sc, (lane >> 4) * 4 + 3);
                #pragma unroll
                for (int ni = 0; ni < 8; ++ni) {
                    oa[qi][ni][0] *= s0; oa[qi][ni][1] *= s1;
                    oa[qi][ni][2] *= s2; oa[qi][ni][3] *= s3;
                }
            }
        }

        s16x8 pa[2][2];
        #pragma unroll
        for (int qi = 0; qi < 2; ++qi) {
            float sum = 0.f;
            #pragma unroll
            for (int kt = 0; kt < 4; ++kt)
                #pragma unroll
                for (int r = 0; r < 4; ++r) {
                    const float p = exp2f(st[qi][kt][r] - m_r[qi]);
                    st[qi][kt][r] = p;
                    sum += p;
                }
            sum += __shfl_xor(sum, 16);
            sum += __shfl_xor(sum, 32);
            l_r[qi] += sum;

            u32 q01[4], q23[4];
            #pragma unroll
            for (int kt = 0; kt < 4; ++kt) {
                q01[kt] = cvtpk(st[qi][kt][0], st[qi][kt][1]);
                q23[kt] = cvtpk(st[qi][kt][2], st[qi][kt][3]);
            }
            #pragma unroll
            for (int ks = 0; ks < 2; ++ks) {
                u32 X = q01[2 * ks], Y = q01[2 * ks + 1];
                swap32(X, Y); swap16(X, Y);
                u32 U = q23[2 * ks], V = q23[2 * ks + 1];
                swap32(U, V); swap16(U, V);
                u32x4 t; t[0] = X; t[1] = U; t[2] = Y; t[3] = V;
                pa[qi][ks] = __builtin_bit_cast(s16x8, t);
            }
        }

        __builtin_amdgcn_s_setprio(1);
        #pragma unroll
        for (int ks = 0; ks < 2; ++ks) {
            const int keyb = ks * 32 + (lane >> 4) * 8;
            #pragma unroll
            for (int ni = 0; ni < 8; ++ni) {
                const int dd = ni * 16 + (lane & 15);
                s16x8 vf = *(const s16x8*)(VtB + ((dd * 128 + keyb * 2) ^ ((dd & 7) << 4)));
                #pragma unroll
                for (int qi = 0; qi < 2; ++qi)
                    oa[qi][ni] = __builtin_amdgcn_mfma_f32_16x16x32_bf16(pa[qi][ks], vf, oa[qi][ni], 0, 0, 0);
            }
        }
        __builtin_amdgcn_s_setprio(0);
    }
    #pragma unroll
    for (int qi = 0; qi < 2; ++qi) {
        #pragma unroll
        for (int r = 0; r < 4; ++r) {
            const float inv = 1.0f / __shfl(l_r[qi], (lane >> 4) * 4 + r);
            const int tout = qtile * 128 + w * 32 + qi * 16 + (lane >> 4) * 4 + r;
            u16* op = o + head + (size_t)tout * 2048 + (lane & 15);
            #pragma unroll
            for (int ni = 0; ni < 8; ++ni)
                op[ni * 16] = f2bf(oa[qi][ni][r] * inv);
        }
    }
}

// ---------------------------------------------------------------------------
extern "C" void kernel_launch(void* const* d_in, const int* in_sizes, int n_in,
                              void* d_out, int out_size, void* d_ws, size_t ws_size,
                              hipStream_t stream)
{
    (void)in_sizes; (void)n_in; (void)out_size; (void)ws_size;
    const float* x    = (const float*)d_in[0];
    const float* wln1 = (const float*)d_in[1];
    const float* wq   = (const float*)d_in[2];
    const float* wk   = (const float*)d_in[3];
    const float* wv   = (const float*)d_in[4];
    const float* wo   = (const float*)d_in[5];
    const float* wln2 = (const float*)d_in[6];
    const float* wg   = (const float*)d_in[7];
    const float* wu   = (const float*)d_in[8];
    const float* wd   = (const float*)d_in[9];
    float* out = (float*)d_out;

    const size_t MB = 1024ull * 1024ull;
    char* ws = (char*)d_ws;
    u16*   arena = (u16*)(ws + 0);          // 32 MB: bf16 weight arena (reused)
    float* hbuf  = (float*)(ws + 32 * MB);  // 32 MB: x + attn residual (fp32)
    u16*   xn    = (u16*)(ws + 64 * MB);    // 16 MB: rmsnorm output (bf16)
    u16*   qb    = (u16*)(ws + 80 * MB);    // 16 MB
    u16*   kbuf  = (u16*)(ws + 96 * MB);    // 16 MB
    u16*   vT    = (u16*)(ws + 112 * MB);   // 16 MB: V transposed [h*128+d][b*2048+t]
    u16*   abuf  = (u16*)(ws + 128 * MB);   // 16 MB (ends 144 MB)
    u16*   gbuf  = (u16*)(ws + 80 * MB);    // 64 MB, aliases q..attn (dead then)

    const int M = 4096, C = 2048, I = 8192;
    const float qscale = 0.1275164899f;     // (1/sqrt(128)) * log2(e)
    dim3 blk(256);
    dim3 blk8(512);

    rmsnorm_k<<<M, blk, 0, stream>>>(x, wln1, xn, C);

    cast_w<<<(C * C) / 2048, blk, 0, stream>>>(wq, arena, C * C);
    gemm8<1, 4><<<dim3((C / 256) * (M / 128)), blk8, 0, stream>>>(xn, arena, nullptr, nullptr, qb, M, C, C, qscale);
    cast_w<<<(C * C) / 2048, blk, 0, stream>>>(wk, arena, C * C);
    gemm8<0, 4><<<dim3((C / 256) * (M / 128)), blk8, 0, stream>>>(xn, arena, nullptr, nullptr, kbuf, M, C, C, 1.f);
    cast_w<<<(C * C) / 2048, blk, 0, stream>>>(wv, arena, C * C);
    // V^T = Wv @ Xn^T : operand-swapped GEMM -> coalesced transposed output
    gemm8<0, 4><<<dim3((M / 256) * (C / 128)), blk8, 0, stream>>>(arena, xn, nullptr, nullptr, vT, C, M, C, 1.f);

    flash_attn<<<dim3(2048 / 128, 32), blk, 0, stream>>>(qb, kbuf, vT, abuf);

    cast_w<<<(C * C) / 2048, blk, 0, stream>>>(wo, arena, C * C);
    gemm8<2, 4><<<dim3((C / 256) * (M / 128)), blk8, 0, stream>>>(abuf, arena, x, nullptr, hbuf, M, C, C, 1.f);

    rmsnorm_k<<<M, blk, 0, stream>>>(hbuf, wln2, xn, C);

    cast_w<<<(I * C) / 2048, blk, 0, stream>>>(wg, arena, I * C);
    gemm8<0, 8><<<dim3((I / 256) * (M / 256)), blk8, 0, stream>>>(xn, arena, nullptr, nullptr, gbuf, M, I, C, 1.f);
    cast_w<<<(I * C) / 2048, blk, 0, stream>>>(wu, arena, I * C);
    gemm8<3, 8><<<dim3((I / 256) * (M / 256)), blk8, 0, stream>>>(xn, arena, nullptr, gbuf, gbuf, M, I, C, 1.f);
    cast_w<<<(C * I) / 2048, blk, 0, stream>>>(wd, arena, C * I);
    gemm8<2, 4><<<dim3((C / 256) * (M / 128)), blk8, 0, stream>>>(gbuf, arena, hbuf, nullptr, out, M, C, I, 1.f);
}